// Round 5
// baseline (754.133 us; speedup 1.0000x reference)
//
#include <hip/hip_runtime.h>
#include <stdint.h>

// HashEncoder (Instant-NGP / HashNeRF): 1M points, 16 levels, 2 feats, 2^19 table.
// R4: single fused kernel. Block = 256 points; loop over levels 0..15 INSIDE the
// kernel (level-major gather preserved: resident block cohorts sweep levels in
// approximate lockstep, so each XCD L2 holds ~1-2 tables at a time, same as the
// old level-major dispatch). Results staged per 8-level phase in an 18KB LDS tile,
// then stored fully coalesced as float4. This removes the 128MB ws write + 128MB
// ws read + second launch (~190us in the old 2-kernel version).
// out stores are non-temporal so the 128MB write stream doesn't evict the hot
// hash tables from L2.
// R8: fix compile error — __builtin_nontemporal_store needs a native clang
// vector type, not HIP_vector_type<float,4>. Store via ext_vector_type(4).

static constexpr int NP = 1048576;
static constexpr int NL = 16;
static constexpr int TPB = 256;
static constexpr uint32_t HMASK = (1u << 19) - 1u;

typedef float f32x4 __attribute__((ext_vector_type(4)));

// res_i = floor(16 * b^i), b = f32(exp((ln512-ln16)/15)) = 1.2599210739135742
// Verified (previous session R1): absmax 2.4e-7 vs reference.
__constant__ float c_res[NL] = {16.f, 20.f, 25.f, 32.f, 40.f, 50.f, 64.f, 80.f,
                                101.f, 128.f, 161.f, 203.f, 256.f, 322.f, 406.f, 512.f};

__device__ __forceinline__ float2 enc_one(
    float x0, float x1, float x2,
    float b0, float b1, float b2,
    float B0, float B1, float B2,
    const float2* __restrict__ tab, float res, float gate)
{
    // index path must be bit-exact vs numpy f32: sub/div/floor only
    float g0 = (B0 - b0) / res;
    float g1 = (B1 - b1) / res;
    float g2 = (B2 - b2) / res;
    float xc0 = fminf(fmaxf(x0, b0), B0);
    float xc1 = fminf(fmaxf(x1, b1), B1);
    float xc2 = fminf(fmaxf(x2, b2), B2);
    float f0 = floorf((xc0 - b0) / g0);
    float f1 = floorf((xc1 - b1) / g1);
    float f2 = floorf((xc2 - b2) / g2);
    // interpolation weights use RAW x (per reference)
    float v0 = f0 * g0 + b0;
    float v1 = f1 * g1 + b1;
    float v2 = f2 * g2 + b2;
    float w0 = (x0 - v0) / ((v0 + g0) - v0);
    float w1 = (x1 - v1) / ((v1 + g1) - v1);
    float w2 = (x2 - v2) / ((v2 + g2) - v2);

    uint32_t u0 = (uint32_t)(int)f0;
    uint32_t u1 = (uint32_t)(int)f1;
    uint32_t u2 = (uint32_t)(int)f2;
    uint32_t ya = u1 * 2654435761u, yb = (u1 + 1u) * 2654435761u;
    uint32_t za = u2 * 805459861u,  zb = (u2 + 1u) * 805459861u;
    uint32_t xa = u0, xb = u0 + 1u;

    // corner index = i*4 + j*2 + k (i on x, j on y, k on z)
    float2 e000 = tab[(xa ^ ya ^ za) & HMASK];
    float2 e001 = tab[(xa ^ ya ^ zb) & HMASK];
    float2 e010 = tab[(xa ^ yb ^ za) & HMASK];
    float2 e011 = tab[(xa ^ yb ^ zb) & HMASK];
    float2 e100 = tab[(xb ^ ya ^ za) & HMASK];
    float2 e101 = tab[(xb ^ ya ^ zb) & HMASK];
    float2 e110 = tab[(xb ^ yb ^ za) & HMASK];
    float2 e111 = tab[(xb ^ yb ^ zb) & HMASK];

    float s0 = 1.f - w0, s1 = 1.f - w1, s2 = 1.f - w2;
    float cx00x = e000.x * s0 + e100.x * w0, cx00y = e000.y * s0 + e100.y * w0;
    float cx01x = e001.x * s0 + e101.x * w0, cx01y = e001.y * s0 + e101.y * w0;
    float cx10x = e010.x * s0 + e110.x * w0, cx10y = e010.y * s0 + e110.y * w0;
    float cx11x = e011.x * s0 + e111.x * w0, cx11y = e011.y * s0 + e111.y * w0;
    float c0x = cx00x * s1 + cx10x * w1, c0y = cx00y * s1 + cx10y * w1;
    float c1x = cx01x * s1 + cx11x * w1, c1y = cx01y * s1 + cx11y * w1;
    float ox = c0x * s2 + c1x * w2;
    float oy = c0y * s2 + c1y * w2;
    return make_float2(ox * gate, oy * gate);
}

// Fused kernel: block = 256 points, levels looped inside (2 phases of 8 levels).
// Phase compute: each thread writes its level result to s[t][m] (pad 9 keeps
// write aliasing at ~4-way, negligible). Phase store: 1024 float4 per block,
// 4 per thread, coalesced in 64B chunks; the complementary half of each 128B
// out line lands in the other phase and merges in L2.
__global__ __launch_bounds__(TPB) void k_enc_fused(
    const float* __restrict__ x, const float* __restrict__ emb,
    const float* __restrict__ lw, const float* __restrict__ bmin,
    const float* __restrict__ bmax, f32x4* __restrict__ out)
{
    __shared__ float2 s[TPB][9];   // 8 levels per phase + pad = 18KB
    int t = threadIdx.x;
    size_t p0 = (size_t)blockIdx.x * TPB;
    int p = (int)p0 + t;

    float x0 = x[3 * p + 0], x1 = x[3 * p + 1], x2 = x[3 * p + 2];
    float b0 = bmin[0], b1 = bmin[1], b2 = bmin[2];
    float B0 = bmax[0], B1 = bmax[1], B2 = bmax[2];

#pragma unroll
    for (int ph = 0; ph < 2; ++ph) {
        if (ph) __syncthreads();   // protect LDS reuse across phases
#pragma unroll
        for (int m = 0; m < 8; ++m) {
            int l = ph * 8 + m;
            float res = c_res[l];
            float gate = 1.0f / (1.0f + expf(-lw[l]));
            const float2* tab = (const float2*)(emb + ((size_t)l << 20));
            s[t][m] = enc_one(x0, x1, x2, b0, b1, b2, B0, B1, B2, tab, res, gate);
        }
        __syncthreads();
        // store this half of out: float4 slot (p*8 + ph*4 + j) covers levels
        // (ph*8 + 2j, ph*8 + 2j + 1)
#pragma unroll
        for (int k = 0; k < 4; ++k) {
            int n = k * TPB + t;      // 0..1023
            int q = n >> 2;           // local point
            int j = n & 3;            // float4 within the half
            float2 a = s[q][2 * j];
            float2 b = s[q][2 * j + 1];
            f32x4 v = {a.x, a.y, b.x, b.y};
            __builtin_nontemporal_store(v, &out[(p0 + (size_t)q) * 8 + ph * 4 + j]);
        }
    }
}

extern "C" void kernel_launch(void* const* d_in, const int* in_sizes, int n_in,
                              void* d_out, int out_size, void* d_ws, size_t ws_size,
                              hipStream_t stream) {
    const float* x    = (const float*)d_in[0];
    const float* emb  = (const float*)d_in[1];
    const float* lw   = (const float*)d_in[2];
    const float* bmin = (const float*)d_in[3];
    const float* bmax = (const float*)d_in[4];
    (void)d_ws; (void)ws_size;

    k_enc_fused<<<NP / TPB, TPB, 0, stream>>>(x, emb, lw, bmin, bmax, (f32x4*)d_out);
}